// Round 3
// baseline (180.396 us; speedup 1.0000x reference)
//
#include <hip/hip_runtime.h>

// Predictor_8924942041234 — 2-hop rule grounding, SINGLE dispatch.
// Round-2 profile showed the 256 MiB ws re-poison fill (40.5 us, 82% HBM peak)
// dominates; prior session measured ~15 us fixed cost per dispatch. Merging
// K1+K2 into one kernel with a manual device-scope grid barrier removes one
// dispatch (~15 us predicted). Cooperative launch failed previously; this
// uses a flag barrier per Guideline 16 (device-scope atomics/fences).
//
// Co-residency: 512 blocks x 256 thr = 2 blocks/CU on 256 CUs; per-block
// LDS ~3 KB, modest VGPR -> capacity 8 blocks/CU; all blocks resident at
// dispatch, so the spin barrier cannot deadlock.
//
// ws layout (bytes):
//   0        headptr[20000] int   (e+1 chain head; <=0 empty; poison 0xAA ok)
//   81920    nodeNext[200000] u32 (prev head (or 0) | r1<<24)
//   881920   nodeBm[200000] u64   (which b's matched hop1 edge e)
//   2481920  flags[512] int       (grid barrier; poison 0xAA != kMagic)

namespace {
constexpr int kNEnt    = 20000;
constexpr int kNRel    = 24;
constexpr int kNEdge   = 200000;
constexpr int kBatch   = 64;
constexpr int kNRules  = 32;
constexpr int kWSz     = kNRel * kNRel;          // 576
constexpr int kScore4  = kBatch * kNEnt / 4;     // 320000 float4 (score)
constexpr int kOut4    = 2 * kScore4;            // 640000 float4 (score+mask)
constexpr int kBlocks  = 512;                    // 2 per CU — co-resident
constexpr int kT       = 256;
constexpr int kGrid    = kBlocks * kT;           // 131072
constexpr int kMagic   = 0x135A79;               // != 0xAAAAAAAA, != 0
}

__global__ void __launch_bounds__(kT) k_fused(
        const int* __restrict__ all_h,
        const int* __restrict__ rem,
        const int* __restrict__ eh,
        const int* __restrict__ er,
        const int* __restrict__ et,
        const int* __restrict__ rb,
        const float* __restrict__ rw,
        const float* __restrict__ bias,
        float* __restrict__ out,
        int* __restrict__ headptr,
        unsigned* __restrict__ nodeNext,
        unsigned long long* __restrict__ nodeBm,
        int* __restrict__ flags) {
    __shared__ int   sh[kBatch];
    __shared__ int   srem[kBatch];
    __shared__ float sW[kWSz];
    const int t   = threadIdx.x;
    const int bid = blockIdx.x;

    for (int i = t; i < kWSz; i += kT) sW[i] = 0.f;
    if (t < kBatch) { sh[t] = all_h[t]; srem[t] = rem[t]; }
    __syncthreads();
    if (t < kNRules)
        atomicAdd(&sW[rb[2 * t] * kNRel + rb[2 * t + 1]], rw[t]);
    // sW first used in phase B, after the grid barrier's __syncthreads.

    const int gid = bid * kT + t;

    // ---- Phase A1: out init (score=bias, mask=1) ----
    for (int i = gid; i < kOut4; i += kGrid) {
        if (i < kScore4)
            ((float4*)out)[i] = ((const float4*)bias)[i % (kNEnt / 4)];
        else
            ((float4*)out)[i] = make_float4(1.f, 1.f, 1.f, 1.f);
    }

    // ---- Phase A2: hop1 frontier chain build ----
    for (int e = gid; e < kNEdge; e += kGrid) {
        int h = eh[e];
        unsigned long long bm = 0ull;
        for (int b = 0; b < kBatch; b++)
            bm |= (unsigned long long)(sh[b] == h) << b;
        if (!bm) continue;
        bool removed = false;
        for (int i = 0; i < kBatch; i++) removed |= (srem[i] == e);
        if (removed) continue;
        int tail = et[e];
        int r1   = er[e];
        int old  = atomicExch(&headptr[tail], e + 1);     // store e+1 (>=1)
        unsigned nxt = (old <= 0) ? 0u : (unsigned)old;   // poison/0 -> end
        nodeNext[e] = nxt | ((unsigned)r1 << 24);
        nodeBm[e]   = bm;
    }

    // ---- Grid barrier (device scope, poison-tolerant) ----
    __threadfence();                 // agent-scope release of phase-A writes
    __syncthreads();                 // whole block done with phase A
    if (t == 0)
        __hip_atomic_store(&flags[bid], kMagic,
                           __ATOMIC_RELEASE, __HIP_MEMORY_SCOPE_AGENT);
    // each thread waits on flags[t] and flags[t+256]
    for (int j = t; j < kBlocks; j += kT) {
        while (__hip_atomic_load(&flags[j],
                                 __ATOMIC_ACQUIRE, __HIP_MEMORY_SCOPE_AGENT)
               != kMagic)
            __builtin_amdgcn_s_sleep(8);
    }
    __syncthreads();                 // all 512 blocks' phase A visible

    // ---- Phase B: hop2 (chain probe + atomicAdd) ----
    for (int e = gid; e < kNEdge; e += kGrid) {
        int h = eh[e];
        int p = headptr[h];
        if (p <= 0) continue;                    // ~97% of edges skip
        bool removed = false;
        for (int i = 0; i < kBatch; i++) removed |= (srem[i] == e);
        if (removed) continue;
        int r2 = er[e];
        int t2 = et[e];
        while (p > 0) {
            int e1 = p - 1;
            unsigned nx           = nodeNext[e1];
            unsigned long long bm = nodeBm[e1];
            float w = sW[((nx >> 24) & 31u) * kNRel + r2];
            while (bm) {
                int b = __ffsll(bm) - 1;
                bm &= bm - 1;
                atomicAdd(&out[b * kNEnt + t2], w);
            }
            p = (int)(nx & 0xFFFFFFu);
        }
    }
}

extern "C" void kernel_launch(void* const* d_in, const int* in_sizes, int n_in,
                              void* d_out, int out_size, void* d_ws, size_t ws_size,
                              hipStream_t stream) {
    const int*   all_h = (const int*)d_in[0];
    // d_in[1] = all_r (unused by the reference)
    const int*   rem   = (const int*)d_in[2];
    const int*   eh    = (const int*)d_in[3];
    const int*   er    = (const int*)d_in[4];
    const int*   et    = (const int*)d_in[5];
    const int*   rb    = (const int*)d_in[6];
    const float* rw    = (const float*)d_in[7];
    const float* bias  = (const float*)d_in[8];
    float* out = (float*)d_out;

    char* ws = (char*)d_ws;
    int*                headptr  = (int*)(ws + 0);
    unsigned*           nodeNext = (unsigned*)(ws + 81920);
    unsigned long long* nodeBm   = (unsigned long long*)(ws + 881920);
    int*                flags    = (int*)(ws + 2481920);

    hipLaunchKernelGGL(k_fused, dim3(kBlocks), dim3(kT), 0, stream,
                       all_h, rem, eh, er, et, rb, rw, bias, out,
                       headptr, nodeNext, nodeBm, flags);
}